// Round 2
// baseline (1900.482 us; speedup 1.0000x reference)
//
#include <hip/hip_runtime.h>
#include <hip/hip_fp16.h>
#include <cstdint>
#include <cstddef>

#define TTOK 8192
#define HD   2048
#define ID   4096
#define NE   8
#define NPAIR (TTOK * 2)            // 16384 routed pairs
#define PADROWS (NPAIR + NE * 256)  // 18432 worst-case padded rows (256-row blocks)

typedef _Float16 h8 __attribute__((ext_vector_type(8)));
typedef float    f4 __attribute__((ext_vector_type(4)));

#define VMWAIT(n) asm volatile("s_waitcnt vmcnt(" #n ")" ::: "memory")
#define LGKMWAIT0 asm volatile("s_waitcnt lgkmcnt(0)" ::: "memory")
#define MEMFENCE  asm volatile("" ::: "memory")

__device__ __forceinline__ void async_cp16(const void* g, void* l) {
  __builtin_amdgcn_global_load_lds(
      (const __attribute__((address_space(1))) unsigned int*)g,
      (__attribute__((address_space(3))) unsigned int*)l, 16, 0, 0);
}

__device__ __forceinline__ f4 zero4() { f4 z = {0.f, 0.f, 0.f, 0.f}; return z; }

// ---------------- fp32 -> f16 convert ----------------
__global__ void cvt_kernel(const float* __restrict__ src, _Float16* __restrict__ dst, size_t n) {
  size_t stride = (size_t)gridDim.x * blockDim.x * 8;
  for (size_t i = ((size_t)blockIdx.x * blockDim.x + threadIdx.x) * 8; i < n; i += stride) {
    const float4* s = (const float4*)(src + i);
    float4 a = s[0], b = s[1];
    h8 o;
    o[0] = (_Float16)a.x; o[1] = (_Float16)a.y; o[2] = (_Float16)a.z; o[3] = (_Float16)a.w;
    o[4] = (_Float16)b.x; o[5] = (_Float16)b.y; o[6] = (_Float16)b.z; o[7] = (_Float16)b.w;
    *(h8*)(dst + i) = o;
  }
}

// ---------------- gate: wave per token, 8 dots, top-2 ----------------
__global__ __launch_bounds__(256) void gate_kernel(
    const float* __restrict__ x, const float* __restrict__ gw,
    int* __restrict__ counts, int* __restrict__ tids, float* __restrict__ tw) {
  int lane = threadIdx.x & 63;
  int t = blockIdx.x * 4 + (threadIdx.x >> 6);
  const float* xr = x + (size_t)t * HD;
  float acc[NE];
#pragma unroll
  for (int e = 0; e < NE; e++) acc[e] = 0.f;
  for (int j = lane; j < HD; j += 64) {
    float xv = xr[j];
#pragma unroll
    for (int e = 0; e < NE; e++) acc[e] += xv * gw[e * HD + j];
  }
#pragma unroll
  for (int off = 32; off > 0; off >>= 1) {
#pragma unroll
    for (int e = 0; e < NE; e++) acc[e] += __shfl_xor(acc[e], off, 64);
  }
  if (lane == 0) {
    int e0 = 0; float v0 = acc[0];
#pragma unroll
    for (int e = 1; e < NE; e++) if (acc[e] > v0) { v0 = acc[e]; e0 = e; }
    int e1 = -1; float v1 = -1e30f;
#pragma unroll
    for (int e = 0; e < NE; e++) if (e != e0 && acc[e] > v1) { v1 = acc[e]; e1 = e; }
    float b = __expf(v1 - v0);
    float w0 = 1.f / (1.f + b);
    tids[2 * t] = e0; tids[2 * t + 1] = e1;
    tw[2 * t] = w0;   tw[2 * t + 1] = b * w0;
    atomicAdd(&counts[e0], 1); atomicAdd(&counts[e1], 1);
  }
}

// ---------------- scan: per-expert 256-padded offsets ----------------
__global__ void scan_kernel(const int* __restrict__ counts, int* __restrict__ offs,
                            int* __restrict__ cursor) {
  if (threadIdx.x == 0 && blockIdx.x == 0) {
    int off = 0;
    for (int e = 0; e < NE; e++) {
      offs[e] = off; cursor[e] = off;
      off += ((counts[e] + 255) >> 8) << 8;
    }
    offs[NE] = off;
  }
}

// ---------------- scatter tokens ----------------
__global__ void scatter_kernel(const int* __restrict__ tids, const float* __restrict__ tw,
                               int* __restrict__ cursor, int* __restrict__ perm,
                               float* __restrict__ pw) {
  int t = blockIdx.x * 256 + threadIdx.x;
#pragma unroll
  for (int k = 0; k < 2; k++) {
    int e = tids[2 * t + k];
    int pos = atomicAdd(&cursor[e], 1);
    perm[pos] = t; pw[pos] = tw[2 * t + k];
  }
}

// ---------------- mark padding ----------------
__global__ void padfill_kernel(const int* __restrict__ counts, const int* __restrict__ offs,
                               int* __restrict__ perm) {
  int s = blockIdx.x * 256 + threadIdx.x;
#pragma unroll
  for (int e = 0; e < NE; e++) {
    if (s >= offs[e] + counts[e] && s < offs[e + 1]) perm[s] = -1;
  }
}

// ============================================================================
// gemm1: h = silu(x@Wg^T) * (x@Wu^T).  BM=256, B-tile = 128 Wg rows + 128 Wu
// rows (matching columns -> in-register silu fusion). BK=32, 4-buffer LDS
// ring (128 KiB), counted vmcnt, XOR-swizzled chunks, setprio on MFMA.
// A (gathered x rows) reg-staged fp32->f16 with issue-early/write-late split.
// ============================================================================
__global__ __launch_bounds__(512, 2) void gemm1_kernel(
    const float* __restrict__ x, const _Float16* __restrict__ wsh,
    const int* __restrict__ counts, const int* __restrict__ offs,
    const int* __restrict__ perm, _Float16* __restrict__ hbuf) {
  // T1: XCD-chunked remap; nwg = 32*256 = 8192, 8192/8 = 1024 per XCD.
  int lin = blockIdx.x + gridDim.x * blockIdx.y;
  int wg = (lin & 7) * 1024 + (lin >> 3);
  int bx = wg & 31;            // ntile fastest: A-panel stays L2-hot
  int by = wg >> 5;
  int e = by >> 5, rb = by & 31;
  if (rb >= ((counts[e] + 255) >> 8)) return;
  int row0 = offs[e] + (rb << 8);
  int n0 = bx << 7;            // 128 h-columns per block

  __shared__ _Float16 smem[65536];  // 4 bufs x (A 8192 + B 8192) f16 = 128 KiB
  int tid = threadIdx.x;
  int lane = tid & 63, wid = tid >> 6, wr = wid >> 2, wc = wid & 3;
  int lr = lane & 15, kc = lane >> 4;
  int ach = kc ^ ((lr >> 1) & 3);   // swizzled 16B-chunk for ds_read

  // ---- A reg-staging setup: thread -> row ar, fp32 half ahf ----
  int ar = tid >> 1, ahf = tid & 1;
  int pa = perm[row0 + ar]; if (pa < 0) pa = 0;
  const float* aptr = x + (size_t)pa * HD + ahf * 16;
  int as = (ar >> 1) & 3;
  int aw0 = ar * 32 + (((ahf << 1) ^ as) << 3);
  int aw1 = ar * 32 + ((((ahf << 1) | 1) ^ as) << 3);

  // ---- B gload_lds setup: round j rows j*128 + (tid>>2), pre-swizzled src ----
  int br = tid >> 2;
  int swzc = (tid & 3) ^ ((tid >> 3) & 3);
  const _Float16* bptr0 = wsh + ((size_t)e * 2 * ID + (n0 + br)) * HD + swzc * 8;      // Wg
  const _Float16* bptr1 = wsh + ((size_t)e * 2 * ID + ID + (n0 + br)) * HD + swzc * 8; // Wu

  f4 acc[8][4];
#pragma unroll
  for (int m = 0; m < 8; m++)
#pragma unroll
    for (int n = 0; n < 4; n++) acc[m][n] = zero4();

  float4 fP0, fP1, fP2, fP3, fN0, fN1, fN2, fN3;

  auto stageB = [&](int kt, int b) {
    async_cp16(bptr0 + kt * 32, &smem[b * 16384 + 8192 + tid * 8]);
    async_cp16(bptr1 + kt * 32, &smem[b * 16384 + 8192 + 4096 + tid * 8]);
  };
  auto writeA = [&](int b) {
    h8 o0, o1;
    o0[0]=(_Float16)fP0.x; o0[1]=(_Float16)fP0.y; o0[2]=(_Float16)fP0.z; o0[3]=(_Float16)fP0.w;
    o0[4]=(_Float16)fP1.x; o0[5]=(_Float16)fP1.y; o0[6]=(_Float16)fP1.z; o0[7]=(_Float16)fP1.w;
    o1[0]=(_Float16)fP2.x; o1[1]=(_Float16)fP2.y; o1[2]=(_Float16)fP2.z; o1[3]=(_Float16)fP2.w;
    o1[4]=(_Float16)fP3.x; o1[5]=(_Float16)fP3.y; o1[6]=(_Float16)fP3.z; o1[7]=(_Float16)fP3.w;
    *(h8*)&smem[b * 16384 + aw0] = o0;
    *(h8*)&smem[b * 16384 + aw1] = o1;
  };
  auto compute = [&](int b) {
    int abase = b * 16384, bbase = b * 16384 + 8192;
    h8 af[8], bf[4];
#pragma unroll
    for (int m = 0; m < 8; m++)
      af[m] = *(const h8*)&smem[abase + (wr * 128 + m * 16 + lr) * 32 + ach * 8];
#pragma unroll
    for (int n = 0; n < 4; n++) {
      int rB = (n < 2) ? (wc * 32 + n * 16 + lr) : (128 + wc * 32 + (n - 2) * 16 + lr);
      bf[n] = *(const h8*)&smem[bbase + rB * 32 + ach * 8];
    }
    __builtin_amdgcn_s_setprio(1);
#pragma unroll
    for (int m = 0; m < 8; m++)
#pragma unroll
      for (int n = 0; n < 4; n++)
        acc[m][n] = __builtin_amdgcn_mfma_f32_16x16x32_f16(af[m], bf[n], acc[m][n], 0, 0, 0);
    __builtin_amdgcn_s_setprio(0);
  };

  // ---- prologue: tiles 0..2 staged, A(3) in regs ----
#pragma unroll
  for (int t = 0; t < 3; t++) {
    const float4* p = (const float4*)(aptr + t * 32);
    fP0 = p[0]; fP1 = p[1]; fP2 = p[2]; fP3 = p[3];
    stageB(t, t);
    writeA(t);
  }
  {
    const float4* p = (const float4*)(aptr + 3 * 32);
    fP0 = p[0]; fP1 = p[1]; fP2 = p[2]; fP3 = p[3];
  }
  LGKMWAIT0;  // prologue ds_writes visible before first barrier

  const int NK = HD / 32;  // 64
  for (int k = 0; k <= NK - 4; ++k) {
    int b = k & 3, tb = (k + 3) & 3;
    VMWAIT(8);
    __builtin_amdgcn_s_barrier();
    MEMFENCE;
    if (k + 4 < NK) {
      const float4* p = (const float4*)(aptr + (k + 4) * 32);
      fN0 = p[0]; fN1 = p[1]; fN2 = p[2]; fN3 = p[3];
    }
    stageB(k + 3, tb);
    writeA(tb);              // waits ~vmcnt(8): B pipeline stays in flight
    compute(b);
    fP0 = fN0; fP1 = fN1; fP2 = fN2; fP3 = fN3;
  }
  VMWAIT(2); __builtin_amdgcn_s_barrier(); MEMFENCE; compute((NK - 3) & 3);
  VMWAIT(2); __builtin_amdgcn_s_barrier(); MEMFENCE; compute((NK - 2) & 3);
  VMWAIT(0); __builtin_amdgcn_s_barrier(); MEMFENCE; compute((NK - 1) & 3);

  // ---- epilogue: fused silu(g)*u, f16 store ----
  int hr0 = row0 + wr * 128 + kc * 4;
  int hc0 = n0 + wc * 32 + lr;
#pragma unroll
  for (int m = 0; m < 8; m++)
#pragma unroll
    for (int n = 0; n < 2; n++)
#pragma unroll
      for (int r = 0; r < 4; r++) {
        float g = acc[m][n][r], u = acc[m][n + 2][r];
        float hv = g / (1.f + __expf(-g)) * u;
        hbuf[(size_t)(hr0 + m * 16 + r) * ID + hc0 + n * 16] = (_Float16)hv;
      }
}

// ============================================================================
// gemm2: out[t] += w * (h @ W2^T).  BM=256, BN=256, BK=32, same ring pipeline,
// both operands via swizzled global_load_lds. Scatter-add epilogue.
// ============================================================================
__global__ __launch_bounds__(512, 2) void gemm2_kernel(
    const _Float16* __restrict__ hbuf, const _Float16* __restrict__ w2h,
    const int* __restrict__ counts, const int* __restrict__ offs,
    const int* __restrict__ perm, const float* __restrict__ pw,
    float* __restrict__ out) {
  // T1 remap; nwg = 8*256 = 2048
  int lin = blockIdx.x + gridDim.x * blockIdx.y;
  int wg = (lin & 7) * 256 + (lin >> 3);
  int bx = wg & 7;
  int by = wg >> 3;
  int e = by >> 5, rb = by & 31;
  if (rb >= ((counts[e] + 255) >> 8)) return;
  int row0 = offs[e] + (rb << 8);
  int n0 = bx << 8;   // 256 out-columns

  __shared__ _Float16 smem[65536];
  int tid = threadIdx.x;
  int lane = tid & 63, wid = tid >> 6, wr = wid >> 2, wc = wid & 3;
  int lr = lane & 15, kc = lane >> 4;
  int ach = kc ^ ((lr >> 1) & 3);

  int br = tid >> 2;
  int swzc = (tid & 3) ^ ((tid >> 3) & 3);
  const _Float16* aptr0 = hbuf + (size_t)(row0 + br) * ID + swzc * 8;
  const _Float16* aptr1 = hbuf + (size_t)(row0 + 128 + br) * ID + swzc * 8;
  const _Float16* bptr0 = w2h + ((size_t)e * HD + n0 + br) * ID + swzc * 8;
  const _Float16* bptr1 = w2h + ((size_t)e * HD + n0 + 128 + br) * ID + swzc * 8;

  f4 acc[8][4];
#pragma unroll
  for (int m = 0; m < 8; m++)
#pragma unroll
    for (int n = 0; n < 4; n++) acc[m][n] = zero4();

  auto stage = [&](int kt, int b) {
    async_cp16(aptr0 + kt * 32, &smem[b * 16384 + tid * 8]);
    async_cp16(aptr1 + kt * 32, &smem[b * 16384 + 4096 + tid * 8]);
    async_cp16(bptr0 + kt * 32, &smem[b * 16384 + 8192 + tid * 8]);
    async_cp16(bptr1 + kt * 32, &smem[b * 16384 + 8192 + 4096 + tid * 8]);
  };
  auto compute = [&](int b) {
    int abase = b * 16384, bbase = b * 16384 + 8192;
    h8 af[8], bf[4];
#pragma unroll
    for (int m = 0; m < 8; m++)
      af[m] = *(const h8*)&smem[abase + (wr * 128 + m * 16 + lr) * 32 + ach * 8];
#pragma unroll
    for (int n = 0; n < 4; n++)
      bf[n] = *(const h8*)&smem[bbase + (wc * 64 + n * 16 + lr) * 32 + ach * 8];
    __builtin_amdgcn_s_setprio(1);
#pragma unroll
    for (int m = 0; m < 8; m++)
#pragma unroll
      for (int n = 0; n < 4; n++)
        acc[m][n] = __builtin_amdgcn_mfma_f32_16x16x32_f16(af[m], bf[n], acc[m][n], 0, 0, 0);
    __builtin_amdgcn_s_setprio(0);
  };

  stage(0, 0); stage(1, 1); stage(2, 2);

  const int NK = ID / 32;  // 128
  for (int k = 0; k <= NK - 4; ++k) {
    int b = k & 3, tb = (k + 3) & 3;
    VMWAIT(8);
    __builtin_amdgcn_s_barrier();
    MEMFENCE;
    stage(k + 3, tb);
    compute(b);
  }
  VMWAIT(8); __builtin_amdgcn_s_barrier(); MEMFENCE; compute((NK - 3) & 3);
  VMWAIT(4); __builtin_amdgcn_s_barrier(); MEMFENCE; compute((NK - 2) & 3);
  VMWAIT(0); __builtin_amdgcn_s_barrier(); MEMFENCE; compute((NK - 1) & 3);

  // ---- scatter-add epilogue ----
#pragma unroll
  for (int m = 0; m < 8; m++) {
#pragma unroll
    for (int r = 0; r < 4; r++) {
      int row = row0 + wr * 128 + m * 16 + kc * 4 + r;
      int t = perm[row];
      if (t < 0) continue;
      float w = pw[row];
      float* orow = out + (size_t)t * HD + n0 + wc * 64 + lr;
#pragma unroll
      for (int n = 0; n < 4; n++)
        atomicAdd(orow + n * 16, acc[m][n][r] * w);
    }
  }
}

// ---------------- host launcher ----------------
extern "C" void kernel_launch(void* const* d_in, const int* in_sizes, int n_in,
                              void* d_out, int out_size, void* d_ws, size_t ws_size,
                              hipStream_t stream) {
  const float* x   = (const float*)d_in[0];
  const float* gw  = (const float*)d_in[1];
  const float* wsf = (const float*)d_in[2];
  const float* w2f = (const float*)d_in[3];

  // ---- workspace layout ----
  int* counts  = (int*)d_ws;
  int* offs    = counts + 8;
  int* cursor  = offs + 16;
  int* tids    = cursor + 8;
  float* tw    = (float*)(tids + NPAIR);
  int* perm    = (int*)(tw + NPAIR);
  float* pw    = (float*)(perm + PADROWS);

  char* base = (char*)d_ws;
  size_t off_h   = (size_t)512 * 1024;
  size_t off_wsh = off_h + (size_t)PADROWS * ID * 2;        // +150,994,944
  size_t off_w2h = off_wsh + (size_t)NE * 2 * ID * HD * 2;  // +268,435,456
  size_t need    = off_w2h + (size_t)NE * HD * ID * 2;      // = 554,172,416
  if (ws_size < need) return;  // proven >= 579 MB in round 1

  _Float16* hb  = (_Float16*)(base + off_h);
  _Float16* wsh = (_Float16*)(base + off_wsh);
  _Float16* w2h = (_Float16*)(base + off_w2h);

  size_t nws = (size_t)NE * 2 * ID * HD;
  size_t nw2 = (size_t)NE * HD * ID;

  hipMemsetAsync(counts, 0, 64, stream);
  hipMemsetAsync(d_out, 0, (size_t)out_size * 4, stream);

  cvt_kernel<<<4096, 256, 0, stream>>>(wsf, wsh, nws);
  cvt_kernel<<<4096, 256, 0, stream>>>(w2f, w2h, nw2);
  gate_kernel<<<TTOK / 4, 256, 0, stream>>>(x, gw, counts, tids, tw);
  scan_kernel<<<1, 64, 0, stream>>>(counts, offs, cursor);
  scatter_kernel<<<TTOK / 256, 256, 0, stream>>>(tids, tw, cursor, perm, pw);
  padfill_kernel<<<PADROWS / 256, 256, 0, stream>>>(counts, offs, perm);

  gemm1_kernel<<<dim3(ID / 128, NE * (TTOK / 256)), 512, 0, stream>>>(
      x, wsh, counts, offs, perm, hb);
  gemm2_kernel<<<dim3(HD / 256, NE * (TTOK / 256)), 512, 0, stream>>>(
      hb, w2h, counts, offs, perm, pw, (float*)d_out);
}

// Round 3
// 1462.181 us; speedup vs baseline: 1.2998x; 1.2998x over previous
//
#include <hip/hip_runtime.h>
#include <hip/hip_fp16.h>
#include <cstdint>
#include <cstddef>

#define TTOK 8192
#define HD   2048
#define ID   4096
#define NE   8
#define NPAIR (TTOK * 2)            // 16384 routed pairs
#define PADROWS 18432               // 16384 + 8*256 worst-case padded rows

typedef _Float16 h8 __attribute__((ext_vector_type(8)));
typedef float    f4 __attribute__((ext_vector_type(4)));

#define VMWAIT(n) asm volatile("s_waitcnt vmcnt(" #n ")" ::: "memory")
#define MEMFENCE  asm volatile("" ::: "memory")
#define BAR()     __builtin_amdgcn_s_barrier()

__device__ __forceinline__ void async_cp16(const void* g, void* l) {
  __builtin_amdgcn_global_load_lds(
      (const __attribute__((address_space(1))) unsigned int*)g,
      (__attribute__((address_space(3))) unsigned int*)l, 16, 0, 0);
}

__device__ __forceinline__ f4 zero4() { f4 z = {0.f, 0.f, 0.f, 0.f}; return z; }

// ---------------- fp32 -> f16 convert ----------------
__global__ void cvt_kernel(const float* __restrict__ src, _Float16* __restrict__ dst, size_t n) {
  size_t stride = (size_t)gridDim.x * blockDim.x * 8;
  for (size_t i = ((size_t)blockIdx.x * blockDim.x + threadIdx.x) * 8; i < n; i += stride) {
    const float4* s = (const float4*)(src + i);
    float4 a = s[0], b = s[1];
    h8 o;
    o[0] = (_Float16)a.x; o[1] = (_Float16)a.y; o[2] = (_Float16)a.z; o[3] = (_Float16)a.w;
    o[4] = (_Float16)b.x; o[5] = (_Float16)b.y; o[6] = (_Float16)b.z; o[7] = (_Float16)b.w;
    *(h8*)(dst + i) = o;
  }
}

// ---------------- gate: wave per token, 8 dots, top-2 ----------------
__global__ __launch_bounds__(256) void gate_kernel(
    const float* __restrict__ x, const float* __restrict__ gw,
    int* __restrict__ counts, int* __restrict__ tids, float* __restrict__ tw) {
  int lane = threadIdx.x & 63;
  int t = blockIdx.x * 4 + (threadIdx.x >> 6);
  const float* xr = x + (size_t)t * HD;
  float acc[NE];
#pragma unroll
  for (int e = 0; e < NE; e++) acc[e] = 0.f;
  for (int j = lane; j < HD; j += 64) {
    float xv = xr[j];
#pragma unroll
    for (int e = 0; e < NE; e++) acc[e] += xv * gw[e * HD + j];
  }
#pragma unroll
  for (int off = 32; off > 0; off >>= 1) {
#pragma unroll
    for (int e = 0; e < NE; e++) acc[e] += __shfl_xor(acc[e], off, 64);
  }
  if (lane == 0) {
    int e0 = 0; float v0 = acc[0];
#pragma unroll
    for (int e = 1; e < NE; e++) if (acc[e] > v0) { v0 = acc[e]; e0 = e; }
    int e1 = -1; float v1 = -1e30f;
#pragma unroll
    for (int e = 0; e < NE; e++) if (e != e0 && acc[e] > v1) { v1 = acc[e]; e1 = e; }
    float b = __expf(v1 - v0);
    float w0 = 1.f / (1.f + b);
    tids[2 * t] = e0; tids[2 * t + 1] = e1;
    tw[2 * t] = w0;   tw[2 * t + 1] = b * w0;
    atomicAdd(&counts[e0], 1); atomicAdd(&counts[e1], 1);
  }
}

// ---------------- scan: per-expert 256-padded offsets ----------------
__global__ void scan_kernel(const int* __restrict__ counts, int* __restrict__ offs,
                            int* __restrict__ cursor) {
  if (threadIdx.x == 0 && blockIdx.x == 0) {
    int off = 0;
    for (int e = 0; e < NE; e++) {
      offs[e] = off; cursor[e] = off;
      off += ((counts[e] + 255) >> 8) << 8;
    }
    offs[NE] = off;
  }
}

// ---------------- scatter tokens (records token->slot map) ----------------
__global__ void scatter_kernel(const int* __restrict__ tids, const float* __restrict__ tw,
                               int* __restrict__ cursor, int* __restrict__ perm,
                               float* __restrict__ pw, int* __restrict__ pairpos) {
  int t = blockIdx.x * 256 + threadIdx.x;
#pragma unroll
  for (int k = 0; k < 2; k++) {
    int e = tids[2 * t + k];
    int pos = atomicAdd(&cursor[e], 1);
    perm[pos] = t; pw[pos] = tw[2 * t + k];
    pairpos[2 * t + k] = pos;
  }
}

// ---------------- mark padding ----------------
__global__ void padfill_kernel(const int* __restrict__ counts, const int* __restrict__ offs,
                               int* __restrict__ perm) {
  int s = blockIdx.x * 256 + threadIdx.x;
#pragma unroll
  for (int e = 0; e < NE; e++) {
    if (s >= offs[e] + counts[e] && s < offs[e + 1]) perm[s] = -1;
  }
}

// ============================================================================
// 8-phase 256x256x64 MFMA GEMM skeleton (m201 structure, plain HIP):
//  - LDS 128 KiB: 2 bufs x { Ah0, Ah1, Bh0, Bh1 } halves of 16 KiB (128r x 64k f16)
//  - buffer b holds K-tile (2i+b); 16 phases / 128-K iteration
//  - all staging via global_load_lds, pre-swizzled global source (chunk^row&7)
//  - counted vmcnt(4) at phases 4 and 8 only; never 0 in steady state
//  - swizzled ds_read_b128 (conflict-free), 16 MFMA per phase under setprio
// ============================================================================
#define LA(BB, H) ((BB) * 65536 + (H) * 16384)
#define LB(BB, H) ((BB) * 65536 + 32768 + (H) * 16384)
#define RD(boff) (*(const h8*)(smem + (boff)))

#define LOAD_AF(BB, MH) do { \
  af[0][0] = RD(LA(BB,MH) + amoff + 0*2048 + sa0); \
  af[0][1] = RD(LA(BB,MH) + amoff + 0*2048 + sa1); \
  af[1][0] = RD(LA(BB,MH) + amoff + 1*2048 + sa0); \
  af[1][1] = RD(LA(BB,MH) + amoff + 1*2048 + sa1); \
  af[2][0] = RD(LA(BB,MH) + amoff + 2*2048 + sa0); \
  af[2][1] = RD(LA(BB,MH) + amoff + 2*2048 + sa1); \
  af[3][0] = RD(LA(BB,MH) + amoff + 3*2048 + sa0); \
  af[3][1] = RD(LA(BB,MH) + amoff + 3*2048 + sa1); } while (0)

#define LOAD_BF(BB, NH) do { \
  bf[0][0] = RD(LB(BB,NH) + bnoff + 0*2048 + sa0); \
  bf[0][1] = RD(LB(BB,NH) + bnoff + 0*2048 + sa1); \
  bf[1][0] = RD(LB(BB,NH) + bnoff + 1*2048 + sa0); \
  bf[1][1] = RD(LB(BB,NH) + bnoff + 1*2048 + sa1); } while (0)

#define MM(MH,NH,M,N) \
  acc[MH][NH][M][N] = __builtin_amdgcn_mfma_f32_16x16x32_f16(af[M][0], bf[N][0], acc[MH][NH][M][N], 0, 0, 0); \
  acc[MH][NH][M][N] = __builtin_amdgcn_mfma_f32_16x16x32_f16(af[M][1], bf[N][1], acc[MH][NH][M][N], 0, 0, 0);

#define MFMAQ(MH,NH) do { __builtin_amdgcn_s_setprio(1); \
  MM(MH,NH,0,0) MM(MH,NH,0,1) MM(MH,NH,1,0) MM(MH,NH,1,1) \
  MM(MH,NH,2,0) MM(MH,NH,2,1) MM(MH,NH,3,0) MM(MH,NH,3,1) \
  __builtin_amdgcn_s_setprio(0); } while (0)

#define STG(gp, ldsbyte, kt) do { \
  async_cp16(gp[0] + (size_t)(kt) * 64, smem + (ldsbyte) + (wid * 2 + 0) * 1024 + lane * 16); \
  async_cp16(gp[1] + (size_t)(kt) * 64, smem + (ldsbyte) + (wid * 2 + 1) * 1024 + lane * 16); } while (0)

#define ACC_ZERO() do { \
  _Pragma("unroll") for (int mh = 0; mh < 2; mh++) \
  _Pragma("unroll") for (int nh = 0; nh < 2; nh++) \
  _Pragma("unroll") for (int m = 0; m < 4; m++) \
  _Pragma("unroll") for (int n = 0; n < 2; n++) acc[mh][nh][m][n] = zero4(); } while (0)

#define KLOOP(NI) \
  STG(gA[0], LA(0,0), 0); STG(gA[1], LA(0,1), 0); \
  STG(gB[0], LB(0,0), 0); STG(gB[1], LB(0,1), 0); \
  STG(gA[0], LA(1,0), 1); STG(gB[1], LB(1,1), 1); \
  VMWAIT(4); \
  BAR(); \
  for (int i = 0; i < (NI); ++i) { \
    bool last = (i == (NI) - 1); \
    int kt1 = 2 * i + 1, kt2 = 2 * i + 2, kt3 = 2 * i + 3; \
    /* ph1 */ \
    MEMFENCE; LOAD_AF(0,0); LOAD_BF(0,0); \
    STG(gA[1], LA(1,1), kt1); STG(gB[0], LB(1,0), kt1); \
    BAR(); MEMFENCE; MFMAQ(0,0); BAR(); \
    /* ph2 */ \
    MEMFENCE; LOAD_BF(0,1); \
    BAR(); MEMFENCE; MFMAQ(0,1); BAR(); \
    /* ph3 */ \
    MEMFENCE; LOAD_AF(0,1); \
    if (!last) STG(gA[0], LA(0,0), kt2); \
    BAR(); MEMFENCE; MFMAQ(1,1); BAR(); \
    /* ph4 */ \
    MEMFENCE; LOAD_BF(0,0); \
    if (!last) { STG(gB[1], LB(0,1), kt2); VMWAIT(4); } else { VMWAIT(0); } \
    BAR(); MEMFENCE; MFMAQ(1,0); BAR(); \
    /* ph5 */ \
    MEMFENCE; LOAD_AF(1,0); LOAD_BF(1,0); \
    if (!last) { STG(gA[1], LA(0,1), kt2); STG(gB[0], LB(0,0), kt2); } \
    BAR(); MEMFENCE; MFMAQ(0,0); BAR(); \
    /* ph6 */ \
    MEMFENCE; LOAD_BF(1,1); \
    BAR(); MEMFENCE; MFMAQ(0,1); BAR(); \
    /* ph7 */ \
    MEMFENCE; LOAD_AF(1,1); \
    if (!last) STG(gA[0], LA(1,0), kt3); \
    BAR(); MEMFENCE; MFMAQ(1,1); BAR(); \
    /* ph8 */ \
    MEMFENCE; LOAD_BF(1,0); \
    if (!last) { STG(gB[1], LB(1,1), kt3); VMWAIT(4); } \
    BAR(); MEMFENCE; MFMAQ(1,0); BAR(); \
  }

// ---- gemm1: h = silu(x@Wg^T) * (x@Wu^T); B-half0 = Wg rows, B-half1 = Wu rows ----
__global__ __launch_bounds__(512, 2) void gemm1_kernel(
    const _Float16* __restrict__ xh, const _Float16* __restrict__ wsh,
    const int* __restrict__ counts, const int* __restrict__ offs,
    const int* __restrict__ perm, _Float16* __restrict__ hb) {
  int lin = blockIdx.x + gridDim.x * blockIdx.y;   // 32 x 256
  int wg = (lin & 7) * 1024 + (lin >> 3);          // XCD-chunked (8192 % 8 == 0)
  int bx = wg & 31, by = wg >> 5;
  int e = by >> 5, rb = by & 31;
  if (rb >= ((counts[e] + 255) >> 8)) return;
  int row0 = offs[e] + (rb << 8);
  int n0 = bx << 7;   // 128 h-cols

  __shared__ char smem[131072];
  int tid = threadIdx.x, lane = tid & 63, wid = tid >> 6;
  int wm = wid >> 2, wn = wid & 3;
  int lr = lane & 15, ks = lane >> 4;
  int sa0 = lr * 128 + (((ks)     ^ (lr & 7)) << 4);
  int sa1 = lr * 128 + (((ks + 4) ^ (lr & 7)) << 4);
  int amoff = wm * 8192;
  int bnoff = wn * 4096;

  int srow = wid * 16 + (lane >> 3);
  int scol = ((lane & 7) ^ (lane >> 3)) * 8;   // pre-swizzled source chunk
  const _Float16* gA[2][2]; const _Float16* gB[2][2];
#pragma unroll
  for (int h = 0; h < 2; h++)
#pragma unroll
    for (int j = 0; j < 2; j++) {
      int r = row0 + h * 128 + srow + j * 8;
      int pv = perm[r]; if (pv < 0) pv = 0;
      gA[h][j] = xh + (size_t)pv * HD + scol;
      gB[h][j] = wsh + ((size_t)e * 2 * ID + (size_t)h * ID + n0 + srow + j * 8) * HD + scol;
    }

  f4 acc[2][2][4][2];
  h8 af[4][2], bf[2][2];
  ACC_ZERO();

  KLOOP(16)   // HD / 128

  // epilogue: silu(g)*u fused in-register (nh0 = g, nh1 = u, same h-col)
#pragma unroll
  for (int mh = 0; mh < 2; mh++)
#pragma unroll
    for (int m = 0; m < 4; m++)
#pragma unroll
      for (int n = 0; n < 2; n++)
#pragma unroll
        for (int r = 0; r < 4; r++) {
          float g = acc[mh][0][m][n][r], u = acc[mh][1][m][n][r];
          float hv = g / (1.f + __expf(-g)) * u;
          int row = row0 + mh * 128 + wm * 64 + m * 16 + ks * 4 + r;
          int col = n0 + wn * 32 + n * 16 + lr;
          hb[(size_t)row * ID + col] = (_Float16)hv;
        }
}

// ---- gemm2: hb2[pairrow] = h @ W2^T (per-pair rows, combined later) ----
__global__ __launch_bounds__(512, 2) void gemm2_kernel(
    const _Float16* __restrict__ hb, const _Float16* __restrict__ w2h,
    const int* __restrict__ counts, const int* __restrict__ offs,
    _Float16* __restrict__ hb2) {
  int lin = blockIdx.x + gridDim.x * blockIdx.y;   // 8 x 256
  int wg = (lin & 7) * 256 + (lin >> 3);           // 2048 % 8 == 0
  int bx = wg & 7, by = wg >> 3;
  int e = by >> 5, rb = by & 31;
  if (rb >= ((counts[e] + 255) >> 8)) return;
  int row0 = offs[e] + (rb << 8);
  int n0 = bx << 8;   // 256 out-cols

  __shared__ char smem[131072];
  int tid = threadIdx.x, lane = tid & 63, wid = tid >> 6;
  int wm = wid >> 2, wn = wid & 3;
  int lr = lane & 15, ks = lane >> 4;
  int sa0 = lr * 128 + (((ks)     ^ (lr & 7)) << 4);
  int sa1 = lr * 128 + (((ks + 4) ^ (lr & 7)) << 4);
  int amoff = wm * 8192;
  int bnoff = wn * 4096;

  int srow = wid * 16 + (lane >> 3);
  int scol = ((lane & 7) ^ (lane >> 3)) * 8;
  const _Float16* gA[2][2]; const _Float16* gB[2][2];
#pragma unroll
  for (int h = 0; h < 2; h++)
#pragma unroll
    for (int j = 0; j < 2; j++) {
      gA[h][j] = hb + ((size_t)(row0 + h * 128 + srow + j * 8)) * ID + scol;
      gB[h][j] = w2h + ((size_t)e * HD + n0 + h * 128 + srow + j * 8) * ID + scol;
    }

  f4 acc[2][2][4][2];
  h8 af[4][2], bf[2][2];
  ACC_ZERO();

  KLOOP(32)   // ID / 128

#pragma unroll
  for (int mh = 0; mh < 2; mh++)
#pragma unroll
    for (int nh = 0; nh < 2; nh++)
#pragma unroll
      for (int m = 0; m < 4; m++)
#pragma unroll
        for (int n = 0; n < 2; n++)
#pragma unroll
          for (int r = 0; r < 4; r++) {
            int row = row0 + mh * 128 + wm * 64 + m * 16 + ks * 4 + r;
            int col = n0 + nh * 128 + wn * 32 + n * 16 + lr;
            hb2[(size_t)row * HD + col] = (_Float16)acc[mh][nh][m][n][r];
          }
}

// ---- combine: out[t] = pw[p0]*hb2[p0] + pw[p1]*hb2[p1] (deterministic) ----
__global__ __launch_bounds__(256) void combine_kernel(
    const _Float16* __restrict__ hb2, const int* __restrict__ pairpos,
    const float* __restrict__ pw, float* __restrict__ out) {
  int i = blockIdx.x * 256 + threadIdx.x;   // T*HD/8 threads
  int t = i >> 8, g = (i & 255) * 8;
  int p0 = pairpos[2 * t], p1 = pairpos[2 * t + 1];
  float w0 = pw[p0], w1 = pw[p1];
  h8 a = *(const h8*)(hb2 + (size_t)p0 * HD + g);
  h8 b = *(const h8*)(hb2 + (size_t)p1 * HD + g);
  float4 o0, o1;
  o0.x = w0 * (float)a[0] + w1 * (float)b[0];
  o0.y = w0 * (float)a[1] + w1 * (float)b[1];
  o0.z = w0 * (float)a[2] + w1 * (float)b[2];
  o0.w = w0 * (float)a[3] + w1 * (float)b[3];
  o1.x = w0 * (float)a[4] + w1 * (float)b[4];
  o1.y = w0 * (float)a[5] + w1 * (float)b[5];
  o1.z = w0 * (float)a[6] + w1 * (float)b[6];
  o1.w = w0 * (float)a[7] + w1 * (float)b[7];
  *(float4*)(out + (size_t)t * HD + g) = o0;
  *(float4*)(out + (size_t)t * HD + g + 4) = o1;
}

// ---------------- host launcher ----------------
extern "C" void kernel_launch(void* const* d_in, const int* in_sizes, int n_in,
                              void* d_out, int out_size, void* d_ws, size_t ws_size,
                              hipStream_t stream) {
  const float* x   = (const float*)d_in[0];
  const float* gw  = (const float*)d_in[1];
  const float* wsf = (const float*)d_in[2];
  const float* w2f = (const float*)d_in[3];

  // ---- meta region (ints, < 512 KB) ----
  int* counts   = (int*)d_ws;            // 8
  int* offs     = counts + 8;            // 16
  int* cursor   = offs + 16;             // 8
  int* tids     = cursor + 8;            // 16384
  float* tw     = (float*)(tids + NPAIR);
  int* perm     = (int*)(tw + NPAIR);    // 18432
  float* pw     = (float*)(perm + PADROWS);
  int* pairpos  = (int*)(pw + PADROWS);  // 16384

  char* base = (char*)d_ws;
  size_t off_xh  = (size_t)512 * 1024;                       // xh: 33,554,432
  size_t off_hb  = off_xh + (size_t)TTOK * HD * 2;           // hb: 150,994,944
  size_t off_big = off_hb + (size_t)PADROWS * ID * 2;        // BIG: 268,435,456
  size_t need    = off_big + (size_t)NE * 2 * ID * HD * 2;   // = 453,509,120
  if (ws_size < need) return;

  _Float16* xh  = (_Float16*)(base + off_xh);
  _Float16* hb  = (_Float16*)(base + off_hb);
  _Float16* wsh = (_Float16*)(base + off_big);                       // live: gemm1
  _Float16* w2h = (_Float16*)(base + off_big);                       // live: gemm2 (overwrites wsh)
  _Float16* hb2 = (_Float16*)(base + off_big + (size_t)NE * HD * ID * 2);  // BIG tail

  hipMemsetAsync(counts, 0, 64, stream);

  cvt_kernel<<<2048, 256, 0, stream>>>(x, xh, (size_t)TTOK * HD);
  cvt_kernel<<<4096, 256, 0, stream>>>(wsf, wsh, (size_t)NE * 2 * ID * HD);
  gate_kernel<<<TTOK / 4, 256, 0, stream>>>(x, gw, counts, tids, tw);
  scan_kernel<<<1, 64, 0, stream>>>(counts, offs, cursor);
  scatter_kernel<<<TTOK / 256, 256, 0, stream>>>(tids, tw, cursor, perm, pw, pairpos);
  padfill_kernel<<<PADROWS / 256, 256, 0, stream>>>(counts, offs, perm);

  gemm1_kernel<<<dim3(ID / 128, NE * 32), 512, 0, stream>>>(
      xh, wsh, counts, offs, perm, hb);

  // Ws^f16 dead after gemm1 -> convert W2 into the same region
  cvt_kernel<<<4096, 256, 0, stream>>>(w2f, w2h, (size_t)NE * HD * ID);

  gemm2_kernel<<<dim3(HD / 256, NE * 32), 512, 0, stream>>>(
      hb, w2h, counts, offs, hb2);

  combine_kernel<<<(TTOK * HD / 8) / 256, 256, 0, stream>>>(
      hb2, pairpos, pw, (float*)d_out);
}

// Round 4
// 1426.042 us; speedup vs baseline: 1.3327x; 1.0253x over previous
//
#include <hip/hip_runtime.h>
#include <hip/hip_fp16.h>
#include <cstdint>
#include <cstddef>

#define TTOK 8192
#define HD   2048
#define ID   4096
#define NE   8
#define NPAIR (TTOK * 2)            // 16384 routed pairs
#define PADROWS 18432               // 16384 + 8*256 worst-case padded rows

typedef _Float16 h8 __attribute__((ext_vector_type(8)));
typedef float    f4 __attribute__((ext_vector_type(4)));

#define VMWAIT(n) asm volatile("s_waitcnt vmcnt(" #n ")" ::: "memory")
#define MEMFENCE  asm volatile("" ::: "memory")
#define BAR()     __builtin_amdgcn_s_barrier()

__device__ __forceinline__ void async_cp16(const void* g, void* l) {
  __builtin_amdgcn_global_load_lds(
      (const __attribute__((address_space(1))) unsigned int*)g,
      (__attribute__((address_space(3))) unsigned int*)l, 16, 0, 0);
}

__device__ __forceinline__ f4 zero4() { f4 z = {0.f, 0.f, 0.f, 0.f}; return z; }

// ---------------- fp32 -> f16 convert (NT: non-temporal store) ----------------
template <bool NT>
__global__ void cvt_kernel(const float* __restrict__ src, _Float16* __restrict__ dst, size_t n) {
  size_t stride = (size_t)gridDim.x * blockDim.x * 8;
  for (size_t i = ((size_t)blockIdx.x * blockDim.x + threadIdx.x) * 8; i < n; i += stride) {
    const float4* s = (const float4*)(src + i);
    float4 a = s[0], b = s[1];
    h8 o;
    o[0] = (_Float16)a.x; o[1] = (_Float16)a.y; o[2] = (_Float16)a.z; o[3] = (_Float16)a.w;
    o[4] = (_Float16)b.x; o[5] = (_Float16)b.y; o[6] = (_Float16)b.z; o[7] = (_Float16)b.w;
    if constexpr (NT) __builtin_nontemporal_store(o, (h8*)(dst + i));
    else *(h8*)(dst + i) = o;
  }
}

// ---------------- gate: wave per token, 8 dots, top-2 ----------------
__global__ __launch_bounds__(256) void gate_kernel(
    const float* __restrict__ x, const float* __restrict__ gw,
    int* __restrict__ counts, int* __restrict__ tids, float* __restrict__ tw) {
  int lane = threadIdx.x & 63;
  int t = blockIdx.x * 4 + (threadIdx.x >> 6);
  const float* xr = x + (size_t)t * HD;
  float acc[NE];
#pragma unroll
  for (int e = 0; e < NE; e++) acc[e] = 0.f;
  for (int j = lane; j < HD; j += 64) {
    float xv = xr[j];
#pragma unroll
    for (int e = 0; e < NE; e++) acc[e] += xv * gw[e * HD + j];
  }
#pragma unroll
  for (int off = 32; off > 0; off >>= 1) {
#pragma unroll
    for (int e = 0; e < NE; e++) acc[e] += __shfl_xor(acc[e], off, 64);
  }
  if (lane == 0) {
    int e0 = 0; float v0 = acc[0];
#pragma unroll
    for (int e = 1; e < NE; e++) if (acc[e] > v0) { v0 = acc[e]; e0 = e; }
    int e1 = -1; float v1 = -1e30f;
#pragma unroll
    for (int e = 0; e < NE; e++) if (e != e0 && acc[e] > v1) { v1 = acc[e]; e1 = e; }
    float b = __expf(v1 - v0);
    float w0 = 1.f / (1.f + b);
    tids[2 * t] = e0; tids[2 * t + 1] = e1;
    tw[2 * t] = w0;   tw[2 * t + 1] = b * w0;
    atomicAdd(&counts[e0], 1); atomicAdd(&counts[e1], 1);
  }
}

// ---------------- scan: per-expert 256-padded offsets ----------------
__global__ void scan_kernel(const int* __restrict__ counts, int* __restrict__ offs,
                            int* __restrict__ cursor) {
  if (threadIdx.x == 0 && blockIdx.x == 0) {
    int off = 0;
    for (int e = 0; e < NE; e++) {
      offs[e] = off; cursor[e] = off;
      off += ((counts[e] + 255) >> 8) << 8;
    }
    offs[NE] = off;
  }
}

// ---------------- scatter tokens (records token->slot map) ----------------
__global__ void scatter_kernel(const int* __restrict__ tids, const float* __restrict__ tw,
                               int* __restrict__ cursor, int* __restrict__ perm,
                               float* __restrict__ pw, int* __restrict__ pairpos) {
  int t = blockIdx.x * 256 + threadIdx.x;
#pragma unroll
  for (int k = 0; k < 2; k++) {
    int e = tids[2 * t + k];
    int pos = atomicAdd(&cursor[e], 1);
    perm[pos] = t; pw[pos] = tw[2 * t + k];
    pairpos[2 * t + k] = pos;
  }
}

// ---------------- mark padding ----------------
__global__ void padfill_kernel(const int* __restrict__ counts, const int* __restrict__ offs,
                               int* __restrict__ perm) {
  int s = blockIdx.x * 256 + threadIdx.x;
#pragma unroll
  for (int e = 0; e < NE; e++) {
    if (s >= offs[e] + counts[e] && s < offs[e + 1]) perm[s] = -1;
  }
}

// ============================================================================
// 8-phase 256x256x64 MFMA GEMM skeleton (m201 structure, plain HIP):
//  - LDS 128 KiB: 2 bufs x { Ah0, Ah1, Bh0, Bh1 } halves of 16 KiB (128r x 64k f16)
//  - all staging via global_load_lds, pre-swizzled global source (chunk^row&7)
//  - counted vmcnt(4) at phases 4 and 8 only; never 0 in steady state
//  - swizzled ds_read_b128 (conflict-free), 16 MFMA per phase under setprio
//  Block order: PLAIN blockIdx (bx fastest, experts sequential over time) so
//  the single live expert slab stays L3-resident (r3 remap blew L3 capacity).
// ============================================================================
#define LA(BB, H) ((BB) * 65536 + (H) * 16384)
#define LB(BB, H) ((BB) * 65536 + 32768 + (H) * 16384)
#define RD(boff) (*(const h8*)(smem + (boff)))

#define LOAD_AF(BB, MH) do { \
  af[0][0] = RD(LA(BB,MH) + amoff + 0*2048 + sa0); \
  af[0][1] = RD(LA(BB,MH) + amoff + 0*2048 + sa1); \
  af[1][0] = RD(LA(BB,MH) + amoff + 1*2048 + sa0); \
  af[1][1] = RD(LA(BB,MH) + amoff + 1*2048 + sa1); \
  af[2][0] = RD(LA(BB,MH) + amoff + 2*2048 + sa0); \
  af[2][1] = RD(LA(BB,MH) + amoff + 2*2048 + sa1); \
  af[3][0] = RD(LA(BB,MH) + amoff + 3*2048 + sa0); \
  af[3][1] = RD(LA(BB,MH) + amoff + 3*2048 + sa1); } while (0)

#define LOAD_BF(BB, NH) do { \
  bf[0][0] = RD(LB(BB,NH) + bnoff + 0*2048 + sa0); \
  bf[0][1] = RD(LB(BB,NH) + bnoff + 0*2048 + sa1); \
  bf[1][0] = RD(LB(BB,NH) + bnoff + 1*2048 + sa0); \
  bf[1][1] = RD(LB(BB,NH) + bnoff + 1*2048 + sa1); } while (0)

#define MM(MH,NH,M,N) \
  acc[MH][NH][M][N] = __builtin_amdgcn_mfma_f32_16x16x32_f16(af[M][0], bf[N][0], acc[MH][NH][M][N], 0, 0, 0); \
  acc[MH][NH][M][N] = __builtin_amdgcn_mfma_f32_16x16x32_f16(af[M][1], bf[N][1], acc[MH][NH][M][N], 0, 0, 0);

#define MFMAQ(MH,NH) do { __builtin_amdgcn_s_setprio(1); \
  MM(MH,NH,0,0) MM(MH,NH,0,1) MM(MH,NH,1,0) MM(MH,NH,1,1) \
  MM(MH,NH,2,0) MM(MH,NH,2,1) MM(MH,NH,3,0) MM(MH,NH,3,1) \
  __builtin_amdgcn_s_setprio(0); } while (0)

#define STG(gp, ldsbyte, kt) do { \
  async_cp16(gp[0] + (size_t)(kt) * 64, smem + (ldsbyte) + (wid * 2 + 0) * 1024 + lane * 16); \
  async_cp16(gp[1] + (size_t)(kt) * 64, smem + (ldsbyte) + (wid * 2 + 1) * 1024 + lane * 16); } while (0)

#define ACC_ZERO() do { \
  _Pragma("unroll") for (int mh = 0; mh < 2; mh++) \
  _Pragma("unroll") for (int nh = 0; nh < 2; nh++) \
  _Pragma("unroll") for (int m = 0; m < 4; m++) \
  _Pragma("unroll") for (int n = 0; n < 2; n++) acc[mh][nh][m][n] = zero4(); } while (0)

#define KLOOP(NI) \
  STG(gA[0], LA(0,0), 0); STG(gA[1], LA(0,1), 0); \
  STG(gB[0], LB(0,0), 0); STG(gB[1], LB(0,1), 0); \
  STG(gA[0], LA(1,0), 1); STG(gB[1], LB(1,1), 1); \
  VMWAIT(4); \
  BAR(); \
  for (int i = 0; i < (NI); ++i) { \
    bool last = (i == (NI) - 1); \
    int kt1 = 2 * i + 1, kt2 = 2 * i + 2, kt3 = 2 * i + 3; \
    /* ph1 */ \
    MEMFENCE; LOAD_AF(0,0); LOAD_BF(0,0); \
    STG(gA[1], LA(1,1), kt1); STG(gB[0], LB(1,0), kt1); \
    BAR(); MEMFENCE; MFMAQ(0,0); BAR(); \
    /* ph2 */ \
    MEMFENCE; LOAD_BF(0,1); \
    BAR(); MEMFENCE; MFMAQ(0,1); BAR(); \
    /* ph3 */ \
    MEMFENCE; LOAD_AF(0,1); \
    if (!last) STG(gA[0], LA(0,0), kt2); \
    BAR(); MEMFENCE; MFMAQ(1,1); BAR(); \
    /* ph4 */ \
    MEMFENCE; LOAD_BF(0,0); \
    if (!last) { STG(gB[1], LB(0,1), kt2); VMWAIT(4); } else { VMWAIT(0); } \
    BAR(); MEMFENCE; MFMAQ(1,0); BAR(); \
    /* ph5 */ \
    MEMFENCE; LOAD_AF(1,0); LOAD_BF(1,0); \
    if (!last) { STG(gA[1], LA(0,1), kt2); STG(gB[0], LB(0,0), kt2); } \
    BAR(); MEMFENCE; MFMAQ(0,0); BAR(); \
    /* ph6 */ \
    MEMFENCE; LOAD_BF(1,1); \
    BAR(); MEMFENCE; MFMAQ(0,1); BAR(); \
    /* ph7 */ \
    MEMFENCE; LOAD_AF(1,1); \
    if (!last) STG(gA[0], LA(1,0), kt3); \
    BAR(); MEMFENCE; MFMAQ(1,1); BAR(); \
    /* ph8 */ \
    MEMFENCE; LOAD_BF(1,0); \
    if (!last) { STG(gB[1], LB(1,1), kt3); VMWAIT(4); } \
    BAR(); MEMFENCE; MFMAQ(1,0); BAR(); \
  }

// ---- gemm1: h = silu(x@Wg^T) * (x@Wu^T); B-half0 = Wg rows, B-half1 = Wu rows ----
__global__ __launch_bounds__(512, 2) void gemm1_kernel(
    const _Float16* __restrict__ xh, const _Float16* __restrict__ wsh,
    const int* __restrict__ counts, const int* __restrict__ offs,
    const int* __restrict__ perm, _Float16* __restrict__ hb) {
  int bx = blockIdx.x, by = blockIdx.y;   // bx fastest: A-panel L2-shared,
  int e = by >> 5, rb = by & 31;          // experts sequential in time (L3)
  if (rb >= ((counts[e] + 255) >> 8)) return;
  int row0 = offs[e] + (rb << 8);
  int n0 = bx << 7;   // 128 h-cols

  __shared__ char smem[131072];
  int tid = threadIdx.x, lane = tid & 63, wid = tid >> 6;
  int wm = wid >> 2, wn = wid & 3;
  int lr = lane & 15, ks = lane >> 4;
  int sa0 = lr * 128 + (((ks)     ^ (lr & 7)) << 4);
  int sa1 = lr * 128 + (((ks + 4) ^ (lr & 7)) << 4);
  int amoff = wm * 8192;
  int bnoff = wn * 4096;

  int srow = wid * 16 + (lane >> 3);
  int scol = ((lane & 7) ^ (lane >> 3)) * 8;   // pre-swizzled source chunk
  const _Float16* gA[2][2]; const _Float16* gB[2][2];
#pragma unroll
  for (int h = 0; h < 2; h++)
#pragma unroll
    for (int j = 0; j < 2; j++) {
      int r = row0 + h * 128 + srow + j * 8;
      int pv = perm[r]; if (pv < 0) pv = 0;
      gA[h][j] = xh + (size_t)pv * HD + scol;
      gB[h][j] = wsh + ((size_t)e * 2 * ID + (size_t)h * ID + n0 + srow + j * 8) * HD + scol;
    }

  f4 acc[2][2][4][2];
  h8 af[4][2], bf[2][2];
  ACC_ZERO();

  KLOOP(16)   // HD / 128

  // epilogue: silu(g)*u fused in-register (nh0 = g, nh1 = u, same h-col);
  // nt store: hb is read only after the w2 cvt, keep it out of L3
#pragma unroll
  for (int mh = 0; mh < 2; mh++)
#pragma unroll
    for (int m = 0; m < 4; m++)
#pragma unroll
      for (int n = 0; n < 2; n++)
#pragma unroll
        for (int r = 0; r < 4; r++) {
          float g = acc[mh][0][m][n][r], u = acc[mh][1][m][n][r];
          float hv = g / (1.f + __expf(-g)) * u;
          int row = row0 + mh * 128 + wm * 64 + m * 16 + ks * 4 + r;
          int col = n0 + wn * 32 + n * 16 + lr;
          __builtin_nontemporal_store((_Float16)hv, hb + (size_t)row * ID + col);
        }
}

// ---- gemm2: hb2[pairrow] = h @ W2^T (per-pair rows, combined later) ----
__global__ __launch_bounds__(512, 2) void gemm2_kernel(
    const _Float16* __restrict__ hb, const _Float16* __restrict__ w2h,
    const int* __restrict__ counts, const int* __restrict__ offs,
    _Float16* __restrict__ hb2) {
  int bx = blockIdx.x, by = blockIdx.y;
  int e = by >> 5, rb = by & 31;
  if (rb >= ((counts[e] + 255) >> 8)) return;
  int row0 = offs[e] + (rb << 8);
  int n0 = bx << 8;   // 256 out-cols

  __shared__ char smem[131072];
  int tid = threadIdx.x, lane = tid & 63, wid = tid >> 6;
  int wm = wid >> 2, wn = wid & 3;
  int lr = lane & 15, ks = lane >> 4;
  int sa0 = lr * 128 + (((ks)     ^ (lr & 7)) << 4);
  int sa1 = lr * 128 + (((ks + 4) ^ (lr & 7)) << 4);
  int amoff = wm * 8192;
  int bnoff = wn * 4096;

  int srow = wid * 16 + (lane >> 3);
  int scol = ((lane & 7) ^ (lane >> 3)) * 8;
  const _Float16* gA[2][2]; const _Float16* gB[2][2];
#pragma unroll
  for (int h = 0; h < 2; h++)
#pragma unroll
    for (int j = 0; j < 2; j++) {
      gA[h][j] = hb + ((size_t)(row0 + h * 128 + srow + j * 8)) * ID + scol;
      gB[h][j] = w2h + ((size_t)e * HD + n0 + h * 128 + srow + j * 8) * ID + scol;
    }

  f4 acc[2][2][4][2];
  h8 af[4][2], bf[2][2];
  ACC_ZERO();

  KLOOP(32)   // ID / 128

#pragma unroll
  for (int mh = 0; mh < 2; mh++)
#pragma unroll
    for (int nh = 0; nh < 2; nh++)
#pragma unroll
      for (int m = 0; m < 4; m++)
#pragma unroll
        for (int n = 0; n < 2; n++)
#pragma unroll
          for (int r = 0; r < 4; r++) {
            int row = row0 + mh * 128 + wm * 64 + m * 16 + ks * 4 + r;
            int col = n0 + nh * 128 + wn * 32 + n * 16 + lr;
            __builtin_nontemporal_store((_Float16)acc[mh][nh][m][n][r],
                                        hb2 + (size_t)row * HD + col);
          }
}

// ---- combine: out[t] = pw[p0]*hb2[p0] + pw[p1]*hb2[p1] (deterministic) ----
__global__ __launch_bounds__(256) void combine_kernel(
    const _Float16* __restrict__ hb2, const int* __restrict__ pairpos,
    const float* __restrict__ pw, float* __restrict__ out) {
  int i = blockIdx.x * 256 + threadIdx.x;   // T*HD/8 threads
  int t = i >> 8, g = (i & 255) * 8;
  int p0 = pairpos[2 * t], p1 = pairpos[2 * t + 1];
  float w0 = pw[p0], w1 = pw[p1];
  h8 a = *(const h8*)(hb2 + (size_t)p0 * HD + g);
  h8 b = *(const h8*)(hb2 + (size_t)p1 * HD + g);
  f4 o0, o1;
  o0[0] = w0 * (float)a[0] + w1 * (float)b[0];
  o0[1] = w0 * (float)a[1] + w1 * (float)b[1];
  o0[2] = w0 * (float)a[2] + w1 * (float)b[2];
  o0[3] = w0 * (float)a[3] + w1 * (float)b[3];
  o1[0] = w0 * (float)a[4] + w1 * (float)b[4];
  o1[1] = w0 * (float)a[5] + w1 * (float)b[5];
  o1[2] = w0 * (float)a[6] + w1 * (float)b[6];
  o1[3] = w0 * (float)a[7] + w1 * (float)b[7];
  __builtin_nontemporal_store(o0, (f4*)(out + (size_t)t * HD + g));
  __builtin_nontemporal_store(o1, (f4*)(out + (size_t)t * HD + g + 4));
}

// ---------------- host launcher ----------------
extern "C" void kernel_launch(void* const* d_in, const int* in_sizes, int n_in,
                              void* d_out, int out_size, void* d_ws, size_t ws_size,
                              hipStream_t stream) {
  const float* x   = (const float*)d_in[0];
  const float* gw  = (const float*)d_in[1];
  const float* wsf = (const float*)d_in[2];
  const float* w2f = (const float*)d_in[3];

  // ---- meta region (ints, < 512 KB) ----
  int* counts   = (int*)d_ws;            // 8
  int* offs     = counts + 8;            // 16
  int* cursor   = offs + 16;             // 8
  int* tids     = cursor + 8;            // 16384
  float* tw     = (float*)(tids + NPAIR);
  int* perm     = (int*)(tw + NPAIR);    // 18432
  float* pw     = (float*)(perm + PADROWS);
  int* pairpos  = (int*)(pw + PADROWS);  // 16384

  char* base = (char*)d_ws;
  size_t off_xh  = (size_t)512 * 1024;                       // xh: 33,554,432
  size_t off_hb  = off_xh + (size_t)TTOK * HD * 2;           // hb: 150,994,944
  size_t off_big = off_hb + (size_t)PADROWS * ID * 2;        // BIG: 268,435,456
  size_t need    = off_big + (size_t)NE * 2 * ID * HD * 2;   // = 453,509,120
  if (ws_size < need) return;

  _Float16* xh  = (_Float16*)(base + off_xh);
  _Float16* hb  = (_Float16*)(base + off_hb);
  _Float16* wsh = (_Float16*)(base + off_big);                       // live: gemm1
  _Float16* w2h = (_Float16*)(base + off_big);                       // live: gemm2 (overwrites wsh)
  _Float16* hb2 = (_Float16*)(base + off_big + (size_t)NE * HD * ID * 2);  // BIG tail

  hipMemsetAsync(counts, 0, 64, stream);

  cvt_kernel<false><<<2048, 256, 0, stream>>>(x, xh, (size_t)TTOK * HD);
  cvt_kernel<true><<<4096, 256, 0, stream>>>(wsf, wsh, (size_t)NE * 2 * ID * HD);
  gate_kernel<<<TTOK / 4, 256, 0, stream>>>(x, gw, counts, tids, tw);
  scan_kernel<<<1, 64, 0, stream>>>(counts, offs, cursor);
  scatter_kernel<<<TTOK / 256, 256, 0, stream>>>(tids, tw, cursor, perm, pw, pairpos);
  padfill_kernel<<<PADROWS / 256, 256, 0, stream>>>(counts, offs, perm);

  gemm1_kernel<<<dim3(ID / 128, NE * 32), 512, 0, stream>>>(
      xh, wsh, counts, offs, perm, hb);

  // Ws^f16 dead after gemm1 -> convert W2 into the same region (cache-resident:
  // 134 MB < L3, gemm2 reads it immediately)
  cvt_kernel<false><<<4096, 256, 0, stream>>>(w2f, w2h, (size_t)NE * HD * ID);

  gemm2_kernel<<<dim3(HD / 256, NE * 32), 512, 0, stream>>>(
      hb, w2h, counts, offs, hb2);

  combine_kernel<<<(TTOK * HD / 8) / 256, 256, 0, stream>>>(
      hb2, pairpos, pw, (float*)d_out);
}